// Round 1
// 685.795 us; speedup vs baseline: 1.9915x; 1.9915x over previous
//
#include <hip/hip_runtime.h>
#include <utility>

#define NAO   14
#define NOUT  196
#define NBLK  56
#define TS    64           // samples per workgroup (= lanes per wave)
#define ROWP  197          // odd LDS stride -> conflict-free lane-major ds_read
#define OSTR  29           // odd stride for per-wave output staging tile
#define MAXW  28           // max nonzeros per output row (true max is 25)

// ===========================================================================
// Compile-time Wigner-3j CSR tables.
// Math is a line-by-line constexpr port of the previously harness-verified
// device-side setup_kernel (same META/IDXINV tables, same ordering, same
// 1e-10 threshold, same float cast), so the numerical result is identical —
// but now the weights/cols fold into immediate operands of the kernel.
// ===========================================================================

struct Meta { int L, li, lj, rs, cs, off; };
constexpr Meta META[NBLK] = {
  {0,0,0,0,0,0},{0,0,0,0,1,1},{0,0,0,0,2,2},{1,0,1,0,3,14},{1,0,1,0,6,17},{2,0,2,0,9,97},
  {0,0,0,1,0,3},{0,0,0,1,1,4},{0,0,0,1,2,5},{1,0,1,1,3,20},{1,0,1,1,6,23},{2,0,2,1,9,102},
  {0,0,0,2,0,6},{0,0,0,2,1,7},{0,0,0,2,2,8},{1,0,1,2,3,26},{1,0,1,2,6,29},{2,0,2,2,9,107},
  {1,1,0,3,0,32},{1,1,0,3,1,35},{1,1,0,3,2,38},
  {0,1,1,3,3,9},{1,1,1,3,3,62},{2,1,1,3,3,112},
  {0,1,1,3,6,10},{1,1,1,3,6,65},{2,1,1,3,6,117},
  {1,1,2,3,9,41},{2,1,2,3,9,77},{3,1,2,3,9,152},
  {1,1,0,6,0,44},{1,1,0,6,1,47},{1,1,0,6,2,50},
  {0,1,1,6,3,11},{1,1,1,6,3,68},{2,1,1,6,3,122},
  {0,1,1,6,6,12},{1,1,1,6,6,71},{2,1,1,6,6,127},
  {1,1,2,6,9,53},{2,1,2,6,9,82},{3,1,2,6,9,159},
  {2,2,0,9,0,132},{2,2,0,9,1,137},{2,2,0,9,2,142},
  {1,2,1,9,3,56},{2,2,1,9,3,87},{3,2,1,9,3,166},
  {1,2,1,9,6,59},{2,2,1,9,6,92},{3,2,1,9,6,173},
  {0,2,2,9,9,13},{1,2,2,9,9,74},{2,2,2,9,9,147},{3,2,2,9,9,180},{4,2,2,9,9,187}
};
constexpr int IDXINV[NAO] = {0,1,2,4,5,3,7,8,6,11,13,9,12,10};

constexpr double cfact(int n){ double r=1.0; for (int i=2;i<=n;++i) r*=(double)i; return r; }
constexpr double csqrt(double x){
  if (x<=0.0) return 0.0;
  double g = x>1.0 ? x : 1.0;
  for (int i=0;i<200;++i){ double ng = 0.5*(g + x/g); if (ng==g) break; g=ng; }
  return g;
}

constexpr double su2_cg(int j1,int m1,int j2,int m2,int j3,int m3){
  if (m3 != m1+m2) return 0.0;
  int vmin = -j1+j2+m3; if (-j1+m1>vmin) vmin=-j1+m1; if (0>vmin) vmin=0;
  int vmax = j2+j3+m1;  if (j3-j1+j2<vmax) vmax=j3-j1+j2; if (j3+m3<vmax) vmax=j3+m3;
  if (vmax < vmin) return 0.0;
  double c = csqrt((2.0*j3+1.0)*cfact(j3+j1-j2)*cfact(j3-j1+j2)*cfact(j1+j2-j3)*
                   cfact(j3+m3)*cfact(j3-m3) /
                   (cfact(j1+j2+j3+1)*cfact(j1-m1)*cfact(j1+m1)*cfact(j2-m2)*cfact(j2+m2)));
  double s = 0.0;
  for (int v=vmin; v<=vmax; ++v){
    double t = cfact(j2+j3+m1-v)*cfact(j1-m1+v) /
               (cfact(v)*cfact(j3-j1+j2-v)*cfact(j3+m3-v)*cfact(v+j1-j2-m3));
    s += (((v+j2+m2)&1) ? -1.0 : 1.0) * t;
  }
  return c*s;
}

struct QMat { double re[81]; double im[81]; };   // up to 9x9, row-major stride n
constexpr QMat build_q(int l){
  QMat q{};
  int n = 2*l+1;
  const double is2 = 0.70710678118654752440;
  for (int m=-l; m<0; ++m){ q.re[(l+m)*n+(l-m)] = is2; q.im[(l+m)*n+(l+m)] = -is2; }
  q.re[l*n+l] = 1.0;
  for (int m=1; m<=l; ++m){
    double sgn = (m&1) ? -1.0 : 1.0;
    q.re[(l+m)*n+(l+m)] = sgn*is2;
    q.im[(l+m)*n+(l-m)] = sgn*is2;
  }
  int ph = l & 3;                                 // multiply by (-i)^l
  if (ph){
    for (int t=0; t<n*n; ++t){
      double a=q.re[t], b=q.im[t];
      if (ph==1)      { q.re[t]= b; q.im[t]=-a; }
      else if (ph==2) { q.re[t]=-a; q.im[t]=-b; }
      else            { q.re[t]=-b; q.im[t]= a; }
    }
  }
  return q;
}

struct BlockCG { double v[225]; };   // [k][i][j], k stride n2*n3 (selected+normalized)
constexpr BlockCG build_block_cg(int L,int li,int lj){
  int n1=2*L+1, n2=2*li+1, n3=2*lj+1;
  double csu2[225] = {};
  for (int i=0;i<n1;++i)
    for (int k=0;k<n2;++k){
      int m1=i-L, m2=k-li, m3=m1+m2;
      if (m3>=-lj && m3<=lj)
        csu2[(i*n2+k)*n3 + (m3+lj)] = su2_cg(L,m1,li,m2,lj,m3);
    }
  QMat q1 = build_q(L), q2 = build_q(li), q3 = build_q(lj);
  double ccr[225] = {}, cci[225] = {};
  double re2=0.0, im2=0.0;
  for (int a=0;a<n1;++a)
    for (int b=0;b<n2;++b)
      for (int c=0;c<n3;++c){
        double accr=0.0, acci=0.0;
        for (int i=0;i<n1;++i){
          double ar=q1.re[i*n1+a], ai=q1.im[i*n1+a];
          if (ar==0.0 && ai==0.0) continue;
          for (int k=0;k<n2;++k){
            double br=q2.re[k*n2+b], bi=q2.im[k*n2+b];
            if (br==0.0 && bi==0.0) continue;
            double pr=ar*br-ai*bi, pi=ar*bi+ai*br;
            for (int n=0;n<n3;++n){
              double w = csu2[(i*n2+k)*n3+n];
              if (w==0.0) continue;
              double cr = q3.re[n*n3+c], ci = -q3.im[n*n3+c];   // conj(q3)
              accr += w*(pr*cr - pi*ci);
              acci += w*(pr*ci + pi*cr);
            }
          }
        }
        ccr[(a*n2+b)*n3+c]=accr; cci[(a*n2+b)*n3+c]=acci;
        re2 += accr*accr; im2 += acci*acci;
      }
  BlockCG out{};
  bool pick_re = csqrt(re2) >= csqrt(im2);
  double inv = 1.0 / csqrt(pick_re ? re2 : im2);
  for (int t=0; t<n1*n2*n3; ++t) out.v[t] = (pick_re ? ccr[t] : cci[t]) * inv;
  return out;
}

// One constexpr evaluation per block: keeps each under clang's constexpr-step limit.
template<int B> struct BlockV {
  static constexpr BlockCG cg = build_block_cg(META[B].L, META[B].li, META[B].lj);
};

struct Tables {
  int   nnz[NOUT];
  int   cols[NOUT][MAXW];
  float wts[NOUT][MAXW];
  bool  ok;
};

template<int... Bs>
constexpr Tables build_tables_impl(std::integer_sequence<int,Bs...>){
  const BlockCG cgs[NBLK] = { BlockV<Bs>::cg... };
  Tables t{};
  bool seen[NOUT] = {};
  t.ok = true;
  for (int b=0; b<NBLK; ++b){
    int n1=2*META[b].L+1, n2=2*META[b].li+1, n3=2*META[b].lj+1;
    for (int k=0; k<n1; ++k){
      int p = META[b].off + k;
      if (p < 0 || p >= NOUT || seen[p]) { t.ok = false; continue; }
      seen[p] = true;
      int q = 0;
      for (int i=0;i<n2;++i)
        for (int j=0;j<n3;++j){
          double v = cgs[b].v[(k*n2+i)*n3+j];
          if (v > 1e-10 || v < -1e-10){
            if (q >= MAXW) { t.ok = false; continue; }
            int col = IDXINV[META[b].rs+i]*NAO + IDXINV[META[b].cs+j];
            if (col < 0 || col >= NOUT) t.ok = false;
            t.cols[p][q] = col;
            t.wts[p][q]  = (float)v;
            ++q;
          }
        }
      t.nnz[p] = q;
    }
  }
  for (int p=0;p<NOUT;++p) if (!seen[p] || t.nnz[p] < 1) t.ok = false;
  return t;
}
constexpr Tables TBL = build_tables_impl(std::make_integer_sequence<int,NBLK>{});
static_assert(TBL.ok, "Wigner CSR table build failed consistency checks");

// ===========================================================================
// Main kernel.
//  - WG = 256 threads (4 waves), 64 samples staged once in LDS (lane = sample)
//  - wave w computes outputs p in [48w, 48w+48) (wave 3: 52) fully unrolled:
//    each nonzero is  ds_read_b32 xs[lane*197] offset:4*col  +  v_fmac lit, —
//    no table loads, no runtime loop bounds, conflict-free LDS (odd stride).
//  - outputs staged per-wave in LDS (odd stride 29), stored transposed as
//    coalesced float4 runs. No barrier needed after staging barrier (per-wave
//    tiles, wave-synchronous).
// LDS: 64*197*4 + 4*64*29*4 = 80128 B -> 2 WG/CU (8 waves/CU).
// ===========================================================================

template<int P>
__device__ __forceinline__ float dot_row(const float* __restrict__ row){
  float acc = 0.f;
  #pragma unroll
  for (int q = 0; q < TBL.nnz[P]; ++q)
    acc = fmaf(TBL.wts[P][q], row[TBL.cols[P][q]], acc);
  return acc;
}

template<int P0, int... PC>
__device__ __forceinline__ void compute_pack(const float* __restrict__ row,
                                             float* __restrict__ obl,
                                             std::integer_sequence<int,PC...>){
  ((obl[PC] = dot_row<P0+PC>(row)), ...);
}

template<int CH>
__device__ __forceinline__ void store_chunk(const float* __restrict__ ob,
                                            float* __restrict__ out,
                                            int base, int p0, int lane, int total){
  constexpr int Q = CH/4;               // float4s per sample
  #pragma unroll
  for (int it=0; it<Q; ++it){
    int t  = lane + 64*it;
    int s  = t / Q;
    int i4 = t - Q*s;
    int gf = base + s*NOUT + p0 + 4*i4; // float index, 16B-aligned
    if (gf < total){
      const float* o = ob + s*OSTR + 4*i4;
      float4 v; v.x=o[0]; v.y=o[1]; v.z=o[2]; v.w=o[3];
      *(float4*)&out[gf] = v;
    }
  }
}

template<int W>
__device__ __forceinline__ void wave_work(const float* __restrict__ row,
                                          float* __restrict__ obw,
                                          int lane, float* __restrict__ out,
                                          int base, int total){
  constexpr int P0 = 48*W;
  constexpr int C2 = (W==3) ? 28 : 24;
  compute_pack<P0>(row, obw + lane*OSTR, std::make_integer_sequence<int,24>{});
  store_chunk<24>(obw, out, base, P0, lane, total);
  compute_pack<P0+24>(row, obw + lane*OSTR, std::make_integer_sequence<int,C2>{});
  store_chunk<C2>(obw, out, base, P0+24, lane, total);
}

__global__ __launch_bounds__(256, 2)
void expand_kernel(const float* __restrict__ x, float* __restrict__ out, int total){
  __shared__ float xs[TS*ROWP];
  __shared__ float obuf[4][64*OSTR];

  const int tid  = threadIdx.x;
  const int lane = tid & 63;
  const int wid  = tid >> 6;
  const int base = blockIdx.x * (TS*NOUT);

  // Phase 1: coalesced float4 load -> LDS rows at odd stride 197
  for (int t4 = tid; t4 < TS*49; t4 += 256){
    int g = base + 4*t4;
    float4 v = make_float4(0.f,0.f,0.f,0.f);
    if (g < total) v = ((const float4*)x)[(base>>2) + t4];
    int s  = t4/49, i4 = t4 - 49*s;
    int w0 = s*ROWP + 4*i4;
    xs[w0] = v.x; xs[w0+1] = v.y; xs[w0+2] = v.z; xs[w0+3] = v.w;
  }
  __syncthreads();

  const float* row = &xs[lane*ROWP];
  float* ob = obuf[wid];
  switch (wid){
    case 0: wave_work<0>(row, ob, lane, out, base, total); break;
    case 1: wave_work<1>(row, ob, lane, out, base, total); break;
    case 2: wave_work<2>(row, ob, lane, out, base, total); break;
    default: wave_work<3>(row, ob, lane, out, base, total); break;
  }
}

extern "C" void kernel_launch(void* const* d_in, const int* in_sizes, int n_in,
                              void* d_out, int out_size, void* d_ws, size_t ws_size,
                              hipStream_t stream) {
  const float* x = (const float*)d_in[0];
  float* out = (float*)d_out;
  int total   = in_sizes[0];                   // nsamp * 196 floats
  int nsamp   = total / NOUT;
  int nblocks = (nsamp + TS - 1) / TS;
  expand_kernel<<<dim3(nblocks), dim3(256), 0, stream>>>(x, out, total);
}

// Round 2
// 618.822 us; speedup vs baseline: 2.2070x; 1.1082x over previous
//
#include <hip/hip_runtime.h>
#include <utility>

#define NAO   14
#define NOUT  196
#define NBLK  56
#define TS    64           // samples per workgroup (= lanes per wave)
#define ROWP  197          // odd LDS stride -> conflict-free per-lane scalar access
#define MAXW  28           // max nonzeros per output row (true max is 25)
#define NTHR  512          // 8 waves

// ===========================================================================
// Compile-time Wigner-3j CSR tables (harness-verified constexpr math from the
// previous round: same META/IDXINV, same ordering, same 1e-10 threshold, same
// float cast -> numerically identical results).
// ===========================================================================

struct Meta { int L, li, lj, rs, cs, off; };
constexpr Meta META[NBLK] = {
  {0,0,0,0,0,0},{0,0,0,0,1,1},{0,0,0,0,2,2},{1,0,1,0,3,14},{1,0,1,0,6,17},{2,0,2,0,9,97},
  {0,0,0,1,0,3},{0,0,0,1,1,4},{0,0,0,1,2,5},{1,0,1,1,3,20},{1,0,1,1,6,23},{2,0,2,1,9,102},
  {0,0,0,2,0,6},{0,0,0,2,1,7},{0,0,0,2,2,8},{1,0,1,2,3,26},{1,0,1,2,6,29},{2,0,2,2,9,107},
  {1,1,0,3,0,32},{1,1,0,3,1,35},{1,1,0,3,2,38},
  {0,1,1,3,3,9},{1,1,1,3,3,62},{2,1,1,3,3,112},
  {0,1,1,3,6,10},{1,1,1,3,6,65},{2,1,1,3,6,117},
  {1,1,2,3,9,41},{2,1,2,3,9,77},{3,1,2,3,9,152},
  {1,1,0,6,0,44},{1,1,0,6,1,47},{1,1,0,6,2,50},
  {0,1,1,6,3,11},{1,1,1,6,3,68},{2,1,1,6,3,122},
  {0,1,1,6,6,12},{1,1,1,6,6,71},{2,1,1,6,6,127},
  {1,1,2,6,9,53},{2,1,2,6,9,82},{3,1,2,6,9,159},
  {2,2,0,9,0,132},{2,2,0,9,1,137},{2,2,0,9,2,142},
  {1,2,1,9,3,56},{2,2,1,9,3,87},{3,2,1,9,3,166},
  {1,2,1,9,6,59},{2,2,1,9,6,92},{3,2,1,9,6,173},
  {0,2,2,9,9,13},{1,2,2,9,9,74},{2,2,2,9,9,147},{3,2,2,9,9,180},{4,2,2,9,9,187}
};
constexpr int IDXINV[NAO] = {0,1,2,4,5,3,7,8,6,11,13,9,12,10};

constexpr double cfact(int n){ double r=1.0; for (int i=2;i<=n;++i) r*=(double)i; return r; }
constexpr double csqrt(double x){
  if (x<=0.0) return 0.0;
  double g = x>1.0 ? x : 1.0;
  for (int i=0;i<200;++i){ double ng = 0.5*(g + x/g); if (ng==g) break; g=ng; }
  return g;
}

constexpr double su2_cg(int j1,int m1,int j2,int m2,int j3,int m3){
  if (m3 != m1+m2) return 0.0;
  int vmin = -j1+j2+m3; if (-j1+m1>vmin) vmin=-j1+m1; if (0>vmin) vmin=0;
  int vmax = j2+j3+m1;  if (j3-j1+j2<vmax) vmax=j3-j1+j2; if (j3+m3<vmax) vmax=j3+m3;
  if (vmax < vmin) return 0.0;
  double c = csqrt((2.0*j3+1.0)*cfact(j3+j1-j2)*cfact(j3-j1+j2)*cfact(j1+j2-j3)*
                   cfact(j3+m3)*cfact(j3-m3) /
                   (cfact(j1+j2+j3+1)*cfact(j1-m1)*cfact(j1+m1)*cfact(j2-m2)*cfact(j2+m2)));
  double s = 0.0;
  for (int v=vmin; v<=vmax; ++v){
    double t = cfact(j2+j3+m1-v)*cfact(j1-m1+v) /
               (cfact(v)*cfact(j3-j1+j2-v)*cfact(j3+m3-v)*cfact(v+j1-j2-m3));
    s += (((v+j2+m2)&1) ? -1.0 : 1.0) * t;
  }
  return c*s;
}

struct QMat { double re[81]; double im[81]; };
constexpr QMat build_q(int l){
  QMat q{};
  int n = 2*l+1;
  const double is2 = 0.70710678118654752440;
  for (int m=-l; m<0; ++m){ q.re[(l+m)*n+(l-m)] = is2; q.im[(l+m)*n+(l+m)] = -is2; }
  q.re[l*n+l] = 1.0;
  for (int m=1; m<=l; ++m){
    double sgn = (m&1) ? -1.0 : 1.0;
    q.re[(l+m)*n+(l+m)] = sgn*is2;
    q.im[(l+m)*n+(l-m)] = sgn*is2;
  }
  int ph = l & 3;
  if (ph){
    for (int t=0; t<n*n; ++t){
      double a=q.re[t], b=q.im[t];
      if (ph==1)      { q.re[t]= b; q.im[t]=-a; }
      else if (ph==2) { q.re[t]=-a; q.im[t]=-b; }
      else            { q.re[t]=-b; q.im[t]= a; }
    }
  }
  return q;
}

struct BlockCG { double v[225]; };
constexpr BlockCG build_block_cg(int L,int li,int lj){
  int n1=2*L+1, n2=2*li+1, n3=2*lj+1;
  double csu2[225] = {};
  for (int i=0;i<n1;++i)
    for (int k=0;k<n2;++k){
      int m1=i-L, m2=k-li, m3=m1+m2;
      if (m3>=-lj && m3<=lj)
        csu2[(i*n2+k)*n3 + (m3+lj)] = su2_cg(L,m1,li,m2,lj,m3);
    }
  QMat q1 = build_q(L), q2 = build_q(li), q3 = build_q(lj);
  double ccr[225] = {}, cci[225] = {};
  double re2=0.0, im2=0.0;
  for (int a=0;a<n1;++a)
    for (int b=0;b<n2;++b)
      for (int c=0;c<n3;++c){
        double accr=0.0, acci=0.0;
        for (int i=0;i<n1;++i){
          double ar=q1.re[i*n1+a], ai=q1.im[i*n1+a];
          if (ar==0.0 && ai==0.0) continue;
          for (int k=0;k<n2;++k){
            double br=q2.re[k*n2+b], bi=q2.im[k*n2+b];
            if (br==0.0 && bi==0.0) continue;
            double pr=ar*br-ai*bi, pi=ar*bi+ai*br;
            for (int n=0;n<n3;++n){
              double w = csu2[(i*n2+k)*n3+n];
              if (w==0.0) continue;
              double cr = q3.re[n*n3+c], ci = -q3.im[n*n3+c];
              accr += w*(pr*cr - pi*ci);
              acci += w*(pr*ci + pi*cr);
            }
          }
        }
        ccr[(a*n2+b)*n3+c]=accr; cci[(a*n2+b)*n3+c]=acci;
        re2 += accr*accr; im2 += acci*acci;
      }
  BlockCG out{};
  bool pick_re = csqrt(re2) >= csqrt(im2);
  double inv = 1.0 / csqrt(pick_re ? re2 : im2);
  for (int t=0; t<n1*n2*n3; ++t) out.v[t] = (pick_re ? ccr[t] : cci[t]) * inv;
  return out;
}

template<int B> struct BlockV {
  static constexpr BlockCG cg = build_block_cg(META[B].L, META[B].li, META[B].lj);
};

// ---- LDS column swizzle: float4-slot a -> slot (3a mod 49); quads stay
// contiguous (phase-1/4 keep 16B groups), consecutive slots spread across all
// eight 4-bank groups instead of colliding 6-7-way. Baked into CSR columns.
constexpr int tau_map(int a){ return (3*a) % 49; }
constexpr int sig_map(int c){ return 4*tau_map(c>>2) + (c&3); }

struct Tables {
  int   nnz[NOUT];
  int   cols[NOUT][MAXW];   // sigma-mapped LDS column offsets
  float wts[NOUT][MAXW];
  bool  ok;
};

template<int... Bs>
constexpr Tables build_tables_impl(std::integer_sequence<int,Bs...>){
  const BlockCG cgs[NBLK] = { BlockV<Bs>::cg... };
  Tables t{};
  bool seen[NOUT] = {};
  t.ok = true;
  for (int b=0; b<NBLK; ++b){
    int n1=2*META[b].L+1, n2=2*META[b].li+1, n3=2*META[b].lj+1;
    for (int k=0; k<n1; ++k){
      int p = META[b].off + k;
      if (p < 0 || p >= NOUT || seen[p]) { t.ok = false; continue; }
      seen[p] = true;
      int q = 0;
      for (int i=0;i<n2;++i)
        for (int j=0;j<n3;++j){
          double v = cgs[b].v[(k*n2+i)*n3+j];
          if (v > 1e-10 || v < -1e-10){
            if (q >= MAXW) { t.ok = false; continue; }
            int col = IDXINV[META[b].rs+i]*NAO + IDXINV[META[b].cs+j];
            if (col < 0 || col >= NOUT) t.ok = false;
            t.cols[p][q] = sig_map(col);
            t.wts[p][q]  = (float)v;
            ++q;
          }
        }
      t.nnz[p] = q;
    }
  }
  for (int p=0;p<NOUT;++p) if (!seen[p] || t.nnz[p] < 1) t.ok = false;
  return t;
}
constexpr Tables TBL = build_tables_impl(std::make_integer_sequence<int,NBLK>{});
static_assert(TBL.ok, "Wigner CSR table build failed consistency checks");

// ---- 8-way output partition, balanced by sum of panel volumes (~265 each) --
constexpr int NWAVE = 8;
constexpr int WBEG[NWAVE+1] = {0,56,77,94,128,154,171,185,196};

// ===========================================================================
// Main kernel.
//  Phase 1: coalesced float4 load -> xs (odd stride 197, tau-swizzled slots)
//  Phase 2: per-wave straight-line dots; duplicate ds_reads CSE'd by the
//           compiler (pure-read region, accumulators in VGPRs)
//  Phase 3: (barrier) lanes write accumulators back INTO xs at sigma(p)
//  Phase 4: (barrier) phase-1-mirror coalesced float4 store
//  LDS 50432 B; __launch_bounds__(512,4) caps VGPR<=128 -> 2 WG = 16 waves/CU
// ===========================================================================

template<int P>
__device__ __forceinline__ float dot_row(const float* row){
  float acc = 0.f;
  #pragma unroll
  for (int q = 0; q < TBL.nnz[P]; ++q)
    acc = fmaf(TBL.wts[P][q], row[TBL.cols[P][q]], acc);
  return acc;
}

template<int W, int... I>
__device__ __forceinline__ void wave_compute_impl(const float* row, float* acc,
                                                  std::integer_sequence<int,I...>){
  ((acc[I] = dot_row<WBEG[W]+I>(row)), ...);
}
template<int W>
__device__ __forceinline__ void wave_compute(const float* row, float* acc){
  wave_compute_impl<W>(row, acc,
      std::make_integer_sequence<int, WBEG[W+1]-WBEG[W]>{});
}

template<int W, int... I>
__device__ __forceinline__ void wave_store_impl(float* xrow, const float* acc,
                                                std::integer_sequence<int,I...>){
  ((xrow[sig_map(WBEG[W]+I)] = acc[I]), ...);
}
template<int W>
__device__ __forceinline__ void wave_store(float* xrow, const float* acc){
  wave_store_impl<W>(xrow, acc,
      std::make_integer_sequence<int, WBEG[W+1]-WBEG[W]>{});
}

__device__ __forceinline__ int tau_rt(int a){
  int t3 = 3*a;
  t3 -= (t3 >= 98) ? 98 : ((t3 >= 49) ? 49 : 0);
  return t3;
}

__global__ __launch_bounds__(NTHR, 4)
void expand_kernel(const float* __restrict__ x, float* __restrict__ out, int total){
  __shared__ float xs[TS*ROWP];

  const int tid  = threadIdx.x;
  const int lane = tid & 63;
  const int wid  = tid >> 6;
  const int base = blockIdx.x * (TS*NOUT);

  // Phase 1: coalesced float4 load -> LDS (tau-swizzled 16B slots)
  for (int t4 = tid; t4 < TS*49; t4 += NTHR){
    int g = base + 4*t4;
    float4 v = make_float4(0.f,0.f,0.f,0.f);
    if (g < total) v = ((const float4*)x)[(base>>2) + t4];
    int s = t4/49, a = t4 - 49*s;
    float* w = &xs[s*ROWP + 4*tau_rt(a)];
    w[0]=v.x; w[1]=v.y; w[2]=v.z; w[3]=v.w;
  }
  __syncthreads();

  // Phase 2: register-accumulated dots (straight-line, loads CSE'd)
  const float* row = &xs[lane*ROWP];
  float acc[56];
  switch (wid){
    case 0: wave_compute<0>(row, acc); break;
    case 1: wave_compute<1>(row, acc); break;
    case 2: wave_compute<2>(row, acc); break;
    case 3: wave_compute<3>(row, acc); break;
    case 4: wave_compute<4>(row, acc); break;
    case 5: wave_compute<5>(row, acc); break;
    case 6: wave_compute<6>(row, acc); break;
    default: wave_compute<7>(row, acc); break;
  }
  __syncthreads();

  // Phase 3: write outputs back into xs at sigma(p)
  float* xrow = &xs[lane*ROWP];
  switch (wid){
    case 0: wave_store<0>(xrow, acc); break;
    case 1: wave_store<1>(xrow, acc); break;
    case 2: wave_store<2>(xrow, acc); break;
    case 3: wave_store<3>(xrow, acc); break;
    case 4: wave_store<4>(xrow, acc); break;
    case 5: wave_store<5>(xrow, acc); break;
    case 6: wave_store<6>(xrow, acc); break;
    default: wave_store<7>(xrow, acc); break;
  }
  __syncthreads();

  // Phase 4: coalesced float4 store (mirror of phase 1)
  for (int t4 = tid; t4 < TS*49; t4 += NTHR){
    int gf = base + 4*t4;
    if (gf >= total) break;
    int s = t4/49, a = t4 - 49*s;
    const float* o = &xs[s*ROWP + 4*tau_rt(a)];
    float4 v; v.x=o[0]; v.y=o[1]; v.z=o[2]; v.w=o[3];
    *(float4*)&out[gf] = v;
  }
}

extern "C" void kernel_launch(void* const* d_in, const int* in_sizes, int n_in,
                              void* d_out, int out_size, void* d_ws, size_t ws_size,
                              hipStream_t stream) {
  const float* x = (const float*)d_in[0];
  float* out = (float*)d_out;
  int total   = in_sizes[0];                   // nsamp * 196 floats
  int nsamp   = total / NOUT;
  int nblocks = (nsamp + TS - 1) / TS;
  expand_kernel<<<dim3(nblocks), dim3(NTHR), 0, stream>>>(x, out, total);
}